// Round 15
// baseline (582.350 us; speedup 1.0000x reference)
//
#include <hip/hip_runtime.h>
#include <hip/hip_bf16.h>

// y[n,o] = sum_r e[n,r]*(W[r]@x[n])[o] + (e@b)[n,o]
// bf16 GEMM, K = 8256, perm k = il*64 + ih*32 + rh*16 + rl (r = rh*16+rl,
// i = 128*ih + il), bias tile appended. Tile t == il.
// R15: perm puts ih = ks (k-step), so each lane-row's e-block (8 vals) is
// ks-INDEPENDENT -> er[8]/row -> 4 rows/lane affordable (Mw=64). B-read/FLOP
// halves vs R14 (prop. 1/Mw); A-gen VALU/FLOP halves. A never touches LDS
// (gen'd in VALU); LDS = B only, tri-buf 48 KB; ONE barrier/tile, vmcnt(4).
// 256 thr, 4 waves (2M x 2N), wave tile 64x64, acc[4][4]=64 AGPR, 2 blocks/CU.

typedef __attribute__((ext_vector_type(4))) float f32x4;
typedef __attribute__((ext_vector_type(8))) short short8;
typedef __attribute__((ext_vector_type(8))) unsigned short ushort8;

#define R_DIM 32
#define I_DIM 256
#define O_DIM 256
#define KW    8192
#define KEXT  8256
#define BM    128
#define BNB   128             // per-block N (2 N-blocks cover O=256)
#define BK    64
#define NT    (KEXT / BK)     // 129
#define NTHR  256

__device__ __forceinline__ unsigned short f2bf(float f) {
  unsigned u = __builtin_bit_cast(unsigned, f);
  u += 0x7FFFu + ((u >> 16) & 1u);  // RNE
  return (unsigned short)(u >> 16);
}

__device__ __forceinline__ unsigned pk2(float a, float b) {
  __hip_bfloat162 h = __float22bfloat162_rn(make_float2(a, b));  // v_cvt_pk_bf16_f32
  unsigned u;
  __builtin_memcpy(&u, &h, sizeof(u));
  return u;
}

__device__ __forceinline__ void gld_lds16(const void* g, void* l) {
  __builtin_amdgcn_global_load_lds(
      (const __attribute__((address_space(1))) unsigned int*)g,
      (__attribute__((address_space(3))) unsigned int*)l, 16, 0, 0);
}

// ---- prep: Wb[o][k], k = il*64 + ih*32 + rh*16 + rl; bias block appended ----
__global__ void prep_w(const float* __restrict__ W, const float* __restrict__ b,
                       unsigned short* __restrict__ Wb) {
  const int id = blockIdx.x * 256 + threadIdx.x;   // 256 * 2064 threads exactly
  const int o  = id / (KEXT / 4);
  const int k4 = (id - o * (KEXT / 4)) * 4;
  float v[4];
  if (k4 < KW) {
    const int il = k4 >> 6;
    const int c  = k4 & 63;
    const int ih = (c >> 5) & 1;
    const int rh = (c >> 4) & 1;
    const int rl = c & 15;                 // 0,4,8,12
    const int i  = 128 * ih + il;
#pragma unroll
    for (int j = 0; j < 4; ++j)
      v[j] = W[((size_t)((rh * 16 + rl + j) * O_DIM + o)) * I_DIM + i];
  } else {
    const int c  = k4 - KW;
    const int ih = (c >> 5) & 1;
    const int rh = (c >> 4) & 1;
    const int rl = c & 15;
#pragma unroll
    for (int j = 0; j < 4; ++j)
      v[j] = (ih == 0) ? b[(rh * 16 + rl + j) * O_DIM + o] : 0.f;
  }
  uint2 pk;
  pk.x = pk2(v[0], v[1]);
  pk.y = pk2(v[2], v[3]);
  *(uint2*)&Wb[(size_t)o * KEXT + k4] = pk;
}

// ---- main: 256 thr, 4 waves (2M x 2N), wave tile 64x64, B-only LDS ----
__global__ __launch_bounds__(NTHR) void lkg15(
    const float* __restrict__ x, const float* __restrict__ e,
    const unsigned short* __restrict__ Wb, float* __restrict__ out, int Ntot) {
  __shared__ unsigned short Bl[3][BNB * BK];   // 3 x 16 KB = 48 KB -> 2 blocks/CU

  const int tid  = threadIdx.x;
  const int lane = tid & 63;
  const int w    = tid >> 6;     // 0..3
  const int wr   = w >> 1;       // 0..1  (M, 64-row strips)
  const int wc   = w & 1;        // 0..1  (N, 64-col halves)
  const int l15  = lane & 15;
  const int lh   = lane >> 4;    // 0..3
  const int sx   = (l15 & 7) << 4;
  const int kb0  = lh << 4;

  const int mi = (int)blockIdx.x >> 1;     // M-tile
  const int ni = (int)blockIdx.x & 1;      // N-half
  const int m0 = mi * BM;
  const unsigned short* WbN = Wb + (size_t)(ni * BNB) * KEXT;

  // B gld_lds source-side swizzle (rule #21: linear dest + inverse-swz source)
  const int bro = lane >> 3;
  const int bch = (lane & 7) ^ bro;

  // lane's e-col block (ks-independent!): r = (lh>>1)*16 + (lh&1)*8 + j
  const int ebase = (lh >> 1) * 16 + (lh & 1) * 8;

  // 4 A-rows per lane: rg[q] = m0 + wr*64 + q*16 + l15 (clamped)
  int rg[4];
#pragma unroll
  for (int q = 0; q < 4; ++q) rg[q] = min(m0 + wr * 64 + q * 16 + l15, Ntot - 1);

  float er[4][8];
#pragma unroll
  for (int q = 0; q < 4; ++q) {
    const float4 ea = *(const float4*)&e[(size_t)rg[q] * R_DIM + ebase];
    const float4 eb4 = *(const float4*)&e[(size_t)rg[q] * R_DIM + ebase + 4];
    er[q][0] = ea.x; er[q][1] = ea.y; er[q][2] = ea.z; er[q][3] = ea.w;
    er[q][4] = eb4.x; er[q][5] = eb4.y; er[q][6] = eb4.z; er[q][7] = eb4.w;
  }
  const float* xb0 = x + (size_t)rg[0] * I_DIM;
  const float* xb1 = x + (size_t)rg[1] * I_DIM;
  const float* xb2 = x + (size_t)rg[2] * I_DIM;
  const float* xb3 = x + (size_t)rg[3] * I_DIM;

  f32x4 acc[4][4];
#pragma unroll
  for (int a = 0; a < 4; ++a)
#pragma unroll
    for (int c = 0; c < 4; ++c) acc[a][c] = (f32x4){0.f, 0.f, 0.f, 0.f};

  auto issueB4 = [&](unsigned short* Bd, int t2) {
    const size_t k0 = (size_t)t2 * BK;
#pragma unroll
    for (int g = 0; g < 4; ++g)
      gld_lds16(WbN + (size_t)(w * 32 + g * 8 + bro) * KEXT + k0 + bch * 8,
                Bd + (w * 32 + g * 8) * BK);
  };
  auto rdB = [&](const unsigned short* Bb, int ks, int fc) -> short8 {
    const int row = wc * 64 + fc * 16 + l15;
    return *(const short8*)((const char*)Bb + row * 128 + ((ks * 64 + kb0) ^ sx));
  };

  // one tile: issue B(t+2), per ks {read B-frags, per row gen A in VALU + MFMA}
  auto tileF = [&](int t, float s00, float s01, float s10, float s11,
                   float s20, float s21, float s30, float s31, bool pre, int cb) {
    const unsigned short* Bc = Bl[cb];
    unsigned short*       Bw = Bl[cb >= 1 ? cb - 1 : 2];   // (cb+2)%3
    if (pre) issueB4(Bw, t + 2);

#pragma unroll
    for (int ks = 0; ks < 2; ++ks) {
      short8 bf[4];
#pragma unroll
      for (int fc = 0; fc < 4; ++fc) bf[fc] = rdB(Bc, ks, fc);
      const float sq[4] = { ks ? s01 : s00, ks ? s11 : s10,
                            ks ? s21 : s20, ks ? s31 : s30 };
      asm volatile("s_waitcnt lgkmcnt(0)" ::: "memory");
      __builtin_amdgcn_s_setprio(1);
#pragma unroll
      for (int q = 0; q < 4; ++q) {
        uint4 wv;
        wv.x = pk2(sq[q] * er[q][0], sq[q] * er[q][1]);
        wv.y = pk2(sq[q] * er[q][2], sq[q] * er[q][3]);
        wv.z = pk2(sq[q] * er[q][4], sq[q] * er[q][5]);
        wv.w = pk2(sq[q] * er[q][6], sq[q] * er[q][7]);
        short8 af;
        __builtin_memcpy(&af, &wv, 16);
#pragma unroll
        for (int fc = 0; fc < 4; ++fc)
          acc[q][fc] = __builtin_amdgcn_mfma_f32_16x16x32_bf16(af, bf[fc],
                                                               acc[q][fc], 0, 0, 0);
      }
      __builtin_amdgcn_s_setprio(0);
    }
    if (pre) {
      asm volatile("s_waitcnt vmcnt(4)" ::: "memory");  // B(t+1) resident; B(t+2) in flight
    } else {
      asm volatile("s_waitcnt vmcnt(0)" ::: "memory");
    }
    __builtin_amdgcn_s_barrier();
  };

  // ---- prologue: B(0)->Bl[0], B(1)->Bl[1]; x float4 streams for tiles 0..3 ----
  issueB4(Bl[0], 0);
  issueB4(Bl[1], 1);
  float4 xv[4][2];
#pragma unroll
  for (int q = 0; q < 4; ++q) {
    const float* xb = (q == 0) ? xb0 : (q == 1) ? xb1 : (q == 2) ? xb2 : xb3;
    xv[q][0] = *(const float4*)(xb);
    xv[q][1] = *(const float4*)(xb + 128);
  }
  asm volatile("s_waitcnt vmcnt(4)" ::: "memory");   // B(0) resident; B(1) in flight
  __builtin_amdgcn_s_barrier();

  int cb = 0;                                    // t % 3
  for (int u = 0; u < 32; ++u) {
    float4 xn[4][2];
    if (u < 31) {
#pragma unroll
      for (int q = 0; q < 4; ++q) {
        const float* xb = (q == 0) ? xb0 : (q == 1) ? xb1 : (q == 2) ? xb2 : xb3;
        xn[q][0] = *(const float4*)(xb + (u + 1) * 4);
        xn[q][1] = *(const float4*)(xb + 128 + (u + 1) * 4);
      }
    }
    const int t0 = u * 4;
    tileF(t0 + 0, xv[0][0].x, xv[0][1].x, xv[1][0].x, xv[1][1].x,
                  xv[2][0].x, xv[2][1].x, xv[3][0].x, xv[3][1].x, true, cb);
    cb = (cb == 2) ? 0 : cb + 1;
    tileF(t0 + 1, xv[0][0].y, xv[0][1].y, xv[1][0].y, xv[1][1].y,
                  xv[2][0].y, xv[2][1].y, xv[3][0].y, xv[3][1].y, true, cb);
    cb = (cb == 2) ? 0 : cb + 1;
    tileF(t0 + 2, xv[0][0].z, xv[0][1].z, xv[1][0].z, xv[1][1].z,
                  xv[2][0].z, xv[2][1].z, xv[3][0].z, xv[3][1].z, true, cb);
    cb = (cb == 2) ? 0 : cb + 1;
    tileF(t0 + 3, xv[0][0].w, xv[0][1].w, xv[1][0].w, xv[1][1].w,
                  xv[2][0].w, xv[2][1].w, xv[3][0].w, xv[3][1].w, t0 + 3 < 127, cb);
    cb = (cb == 2) ? 0 : cb + 1;
    if (u < 31) {
#pragma unroll
      for (int q = 0; q < 4; ++q) {
        xv[q][0] = xn[q][0];
        xv[q][1] = xn[q][1];
      }
    }
  }
  // bias tile t=128: A'(ks=0) = e (xs=1), A'(ks=1) = 0
  tileF(128, 1.f, 0.f, 1.f, 0.f, 1.f, 0.f, 1.f, 0.f, false, cb);

  // ---- epilogue: C layout col = lane&15, row = (lane>>4)*4 + j ----
#pragma unroll
  for (int q = 0; q < 4; ++q) {
    const int r0 = m0 + wr * 64 + q * 16 + (lane >> 4) * 4;
#pragma unroll
    for (int j = 0; j < 4; ++j) {
      const int rr = r0 + j;
      if (rr < Ntot) {
#pragma unroll
        for (int fc = 0; fc < 4; ++fc) {
          const int col = ni * BNB + wc * 64 + fc * 16 + l15;
          out[(size_t)rr * O_DIM + col] = acc[q][fc][j];
        }
      }
    }
  }
}

// ---- fallback (ws too small): simple 2-barrier kernel reading W/b directly ----
__global__ __launch_bounds__(256) void lkg_fb(
    const float* __restrict__ x, const float* __restrict__ e,
    const float* __restrict__ Wf, const float* __restrict__ bf32,
    float* __restrict__ out, int Ntot) {
  const int FBK = 64;
  const int FNT = (KW + 64) / FBK;
  __shared__ unsigned short Alds[128 * 64];
  __shared__ unsigned short Blds[256 * 64];

  const int tid = threadIdx.x, lane = tid & 63, wid = tid >> 6;
  const int wr = wid >> 1, wc = wid & 1, l15 = lane & 15, lk8 = (lane >> 4) * 8;
  const int m0 = (int)blockIdx.x * 128;
  const int srow = tid >> 1, skq = (tid & 1) * 32;
  const int gr = min(m0 + srow, Ntot - 1);

  f32x4 acc[4][8];
#pragma unroll
  for (int a = 0; a < 4; ++a)
#pragma unroll
    for (int c = 0; c < 8; ++c) acc[a][c] = (f32x4){0.f, 0.f, 0.f, 0.f};

  for (int t = 0; t < FNT; ++t) {
    const int k0 = t * FBK;
    float av[32];
    if (k0 < KW) {
      const int r = k0 >> 8, i0 = k0 & 255;
      const float ev = e[(size_t)gr * R_DIM + r];
#pragma unroll
      for (int p = 0; p < 8; ++p) {
        const float4 xvv = *(const float4*)&x[(size_t)gr * I_DIM + i0 + skq + p * 4];
        av[p * 4 + 0] = xvv.x * ev; av[p * 4 + 1] = xvv.y * ev;
        av[p * 4 + 2] = xvv.z * ev; av[p * 4 + 3] = xvv.w * ev;
      }
    } else {
#pragma unroll
      for (int s2 = 0; s2 < 32; ++s2) {
        const int kk = skq + s2;
        av[s2] = (kk < R_DIM) ? e[(size_t)gr * R_DIM + kk] : 0.f;
      }
    }
    const int bo = tid;
    if (k0 < KW) {
      const int r = k0 >> 8, i0 = k0 & 255;
#pragma unroll
      for (int h = 0; h < 4; ++h) {
        float bv[16];
#pragma unroll
        for (int p = 0; p < 4; ++p) {
          const float4 wv =
              *(const float4*)&Wf[((size_t)(r * O_DIM + bo)) * I_DIM + i0 + h * 16 + p * 4];
          bv[p * 4 + 0] = wv.x; bv[p * 4 + 1] = wv.y;
          bv[p * 4 + 2] = wv.z; bv[p * 4 + 3] = wv.w;
        }
#pragma unroll
        for (int g2 = 0; g2 < 2; ++g2) {
          ushort8 pw;
#pragma unroll
          for (int j = 0; j < 8; ++j) pw[j] = f2bf(bv[g2 * 8 + j]);
          *(ushort8*)&Blds[bo * FBK + h * 16 + g2 * 8] = pw;
        }
      }
    } else {
#pragma unroll
      for (int h = 0; h < 8; ++h) {
        ushort8 pw;
#pragma unroll
        for (int j = 0; j < 8; ++j) {
          const int kk = h * 8 + j;
          pw[j] = (kk < R_DIM) ? f2bf(bf32[kk * O_DIM + bo]) : (unsigned short)0;
        }
        *(ushort8*)&Blds[bo * FBK + h * 8] = pw;
      }
    }
#pragma unroll
    for (int h = 0; h < 4; ++h) {
      ushort8 pw;
#pragma unroll
      for (int j = 0; j < 8; ++j) pw[j] = f2bf(av[h * 8 + j]);
      *(ushort8*)&Alds[srow * FBK + skq + h * 8] = pw;
    }
    __syncthreads();
#pragma unroll
    for (int ks = 0; ks < 2; ++ks) {
      short8 af[4]; short8 bfr[8];
#pragma unroll
      for (int fr = 0; fr < 4; ++fr)
        af[fr] = *(const short8*)&Alds[(wr * 64 + fr * 16 + l15) * FBK + ks * 32 + lk8];
#pragma unroll
      for (int fc = 0; fc < 8; ++fc)
        bfr[fc] = *(const short8*)&Blds[(wc * 128 + fc * 16 + l15) * FBK + ks * 32 + lk8];
#pragma unroll
      for (int fr = 0; fr < 4; ++fr)
#pragma unroll
        for (int fc = 0; fc < 8; ++fc)
          acc[fr][fc] =
              __builtin_amdgcn_mfma_f32_16x16x32_bf16(af[fr], bfr[fc], acc[fr][fc], 0, 0, 0);
    }
    __syncthreads();
  }
#pragma unroll
  for (int fr = 0; fr < 4; ++fr) {
    const int r0 = m0 + wr * 64 + fr * 16 + (lane >> 4) * 4;
#pragma unroll
    for (int fc = 0; fc < 8; ++fc) {
      const int col = wc * 128 + fc * 16 + l15;
#pragma unroll
      for (int j = 0; j < 4; ++j) {
        const int rr = r0 + j;
        if (rr < Ntot) out[(size_t)rr * O_DIM + col] = acc[fr][fc][j];
      }
    }
  }
}

extern "C" void kernel_launch(void* const* d_in, const int* in_sizes, int n_in,
                              void* d_out, int out_size, void* d_ws, size_t ws_size,
                              hipStream_t stream) {
  const float* x = (const float*)d_in[0];
  const float* e = (const float*)d_in[1];
  const float* W = (const float*)d_in[2];
  const float* b = (const float*)d_in[3];
  float* out = (float*)d_out;
  const int Ntot = in_sizes[0] / I_DIM;

  const size_t wb_bytes = (size_t)O_DIM * KEXT * sizeof(unsigned short);
  if (ws_size >= wb_bytes) {
    unsigned short* Wb = (unsigned short*)d_ws;
    prep_w<<<(O_DIM * (KEXT / 4)) / 256, 256, 0, stream>>>(W, b, Wb);
    const int nb = ((Ntot + BM - 1) / BM) * 2;
    lkg15<<<nb, NTHR, 0, stream>>>(x, e, Wb, out, Ntot);
  } else {
    lkg_fb<<<(Ntot + 127) / 128, 256, 0, stream>>>(x, e, W, b, out, Ntot);
  }
}

// Round 17
// 579.367 us; speedup vs baseline: 1.0051x; 1.0051x over previous
//
#include <hip/hip_runtime.h>
#include <hip/hip_bf16.h>

// y[n,o] = sum_r e[n,r]*(W[r]@x[n])[o] + (e@b)[n,o]
// One bf16 GEMM, K = 8256: k = il*64 + ih*32 + r (i = 128*ih + il), bias tile appended.
// R17 = R9 (519us best: 512thr, 8 waves 2Mx4N, wave 64x32, A dbuf + B tri-buf 80KB,
// 2 blocks/CU, counted vmcnt(2), XOR-swizzled LDS, 1 barrier/tile) with the MFMA
// shape switched 16x16x32 -> 32x32x16 (ceiling 2075->2382 TF): wave region = 2
// stacked 32x32 frags, acc = 2x f32x16 = 32 AGPR (same), per K-64 tile 12 ds_read
// + 8 MFMA (vs 16+16). Known: frag reads 4-way bank conflict (32 rows vs 8-slot
// XOR window) - 1.58x on LDS that has ~2.5x headroom. (R16 = this, argument-order
// compile fix.)

typedef __attribute__((ext_vector_type(4))) float f32x4;
typedef __attribute__((ext_vector_type(16))) float f32x16;
typedef __attribute__((ext_vector_type(8))) short short8;
typedef __attribute__((ext_vector_type(8))) unsigned short ushort8;

#define R_DIM 32
#define I_DIM 256
#define O_DIM 256
#define KW    8192
#define KEXT  8256            // +64: [8192,8224)=b^T (ih=0), rest 0
#define BM    128
#define BNB   128             // per-block N (2 N-blocks cover O=256)
#define BK    64
#define NT    (KEXT / BK)     // 129
#define NTHR  512

__device__ __forceinline__ unsigned short f2bf(float f) {
  unsigned u = __builtin_bit_cast(unsigned, f);
  u += 0x7FFFu + ((u >> 16) & 1u);  // RNE
  return (unsigned short)(u >> 16);
}

__device__ __forceinline__ unsigned pk2(float a, float b) {
  __hip_bfloat162 h = __float22bfloat162_rn(make_float2(a, b));  // v_cvt_pk_bf16_f32
  unsigned u;
  __builtin_memcpy(&u, &h, sizeof(u));
  return u;
}

__device__ __forceinline__ void gld_lds16(const void* g, void* l) {
  __builtin_amdgcn_global_load_lds(
      (const __attribute__((address_space(1))) unsigned int*)g,
      (__attribute__((address_space(3))) unsigned int*)l, 16, 0, 0);
}

// ---- prep: Wb[o][k] = bf16(W[r,o,i]), k = il*64+ih*32+r, i = 128*ih+il ----
__global__ void prep_w(const float* __restrict__ W, const float* __restrict__ b,
                       unsigned short* __restrict__ Wb) {
  const int id = blockIdx.x * 256 + threadIdx.x;   // 256 * 2064 threads exactly
  const int o  = id / (KEXT / 4);
  const int k4 = (id - o * (KEXT / 4)) * 4;
  float v[4];
  if (k4 < KW) {
    const int r  = k4 & 31;
    const int ih = (k4 >> 5) & 1;
    const int il = k4 >> 6;
    const int i  = 128 * ih + il;
#pragma unroll
    for (int j = 0; j < 4; ++j)
      v[j] = W[((size_t)((r + j) * O_DIM + o)) * I_DIM + i];
  } else {
    const int kk = k4 - KW;
#pragma unroll
    for (int j = 0; j < 4; ++j)
      v[j] = (kk + j < R_DIM) ? b[(kk + j) * O_DIM + o] : 0.f;
  }
  uint2 pk;
  pk.x = pk2(v[0], v[1]);
  pk.y = pk2(v[2], v[3]);
  *(uint2*)&Wb[(size_t)o * KEXT + k4] = pk;
}

// ---- main: 512 thr, 8 waves (2M x 4N), wave tile 64x32 (2x 32x32), 2 blocks/CU ----
__global__ __launch_bounds__(NTHR)
__attribute__((amdgpu_waves_per_eu(4)))
void lkg17(
    const float* __restrict__ x, const float* __restrict__ e,
    const unsigned short* __restrict__ Wb, float* __restrict__ out, int Ntot) {
  __shared__ unsigned short Al[2][BM * BK];    // 2 x 16 KB
  __shared__ unsigned short Bl[3][BNB * BK];   // 3 x 16 KB  (80 KB total -> 2 blocks/CU)

  const int tid  = threadIdx.x;
  const int lane = tid & 63;
  const int w    = tid >> 6;     // 0..7
  const int wr   = w >> 2;       // 0..1  (M, 64-row strips)
  const int wc   = w & 3;        // 0..3  (N, 32-col strips)
  const int l31  = lane & 31;
  const int sx   = (lane & 7) << 4;

  const int mi = (int)blockIdx.x >> 1;     // M-tile
  const int ni = (int)blockIdx.x & 1;      // N-half
  const int m0 = mi * BM;
  const unsigned short* WbN = Wb + (size_t)(ni * BNB) * KEXT;

  const int srow = tid >> 2;               // 0..127: A row this thread stages
  const int q    = tid & 3;                // col quarter: ih = q>>1, r-half = q&1
  const int ih   = q >> 1;
  const int gr   = min(m0 + srow, Ntot - 1);

  // B gld_lds source-side swizzle (rule #21: linear dest + inverse-swz source)
  const int bro = lane >> 3;              // row within 8-row group
  const int bch = (lane & 7) ^ bro;       // pre-swizzled chunk index

  // e r-half in regs: er[j] = e[gr, (q&1)*16 + j]
  float er[16];
#pragma unroll
  for (int p = 0; p < 4; ++p) {
    const float4 ev = *(const float4*)&e[(size_t)gr * R_DIM + (q & 1) * 16 + p * 4];
    er[p * 4 + 0] = ev.x; er[p * 4 + 1] = ev.y;
    er[p * 4 + 2] = ev.z; er[p * 4 + 3] = ev.w;
  }
  const float* xrow = x + (size_t)gr * I_DIM + ih * 128;  // x scalar stream (il = t)
  const float biasx = (ih == 0) ? 1.f : 0.f;              // bias-tile scale

  f32x16 acc0, acc1;
#pragma unroll
  for (int j = 0; j < 16; ++j) { acc0[j] = 0.f; acc1[j] = 0.f; }

  auto issueB2 = [&](unsigned short* Bd, int t2) {
    const size_t k0 = (size_t)t2 * BK;
#pragma unroll
    for (int g = 0; g < 2; ++g)
      gld_lds16(WbN + (size_t)(w * 16 + g * 8 + bro) * KEXT + k0 + bch * 8,
                Bd + (w * 16 + g * 8) * BK);
  };
  auto stageA = [&](unsigned short* Ad, float xs) {
    char* rowp = (char*)(Ad + srow * BK);
    const int sw = (srow & 7) << 4;
    const int qb = q * 32;
    uint4 wv;
    wv.x = pk2(xs * er[0], xs * er[1]);
    wv.y = pk2(xs * er[2], xs * er[3]);
    wv.z = pk2(xs * er[4], xs * er[5]);
    wv.w = pk2(xs * er[6], xs * er[7]);
    *(uint4*)(rowp + ((qb + 0) ^ sw)) = wv;
    uint4 wv2;
    wv2.x = pk2(xs * er[8],  xs * er[9]);
    wv2.y = pk2(xs * er[10], xs * er[11]);
    wv2.z = pk2(xs * er[12], xs * er[13]);
    wv2.w = pk2(xs * er[14], xs * er[15]);
    *(uint4*)(rowp + ((qb + 16) ^ sw)) = wv2;
  };
  // 32x32x16 frag reads: A row = wr*64 + a*32 + l31, B row = wc*32 + l31;
  // k-slice ks (16 k): byte = ks*32 + (lane>>5)*16, XOR sx
  auto compute = [&](const unsigned short* Ab, const unsigned short* Bb) {
#pragma unroll
    for (int ks = 0; ks < 4; ++ks) {
      const int kb = (ks * 32 + ((lane >> 5) << 4)) ^ sx;
      const short8 a0 =
          *(const short8*)((const char*)Ab + (wr * 64 + l31) * 128 + kb);
      const short8 a1 =
          *(const short8*)((const char*)Ab + (wr * 64 + 32 + l31) * 128 + kb);
      const short8 bq =
          *(const short8*)((const char*)Bb + (wc * 32 + l31) * 128 + kb);
      __builtin_amdgcn_s_setprio(1);
      acc0 = __builtin_amdgcn_mfma_f32_32x32x16_bf16(a0, bq, acc0, 0, 0, 0);
      acc1 = __builtin_amdgcn_mfma_f32_32x32x16_bf16(a1, bq, acc1, 0, 0, 0);
      __builtin_amdgcn_s_setprio(0);
    }
  };

  // ---- prologue: A(0)->Al[0]; B(0)->Bl[0], B(1)->Bl[1] (B(1) stays in flight) ----
  float4 xv = *(const float4*)xrow;             // x scalars for tiles 0..3
  stageA(Al[0], xv.x);
  issueB2(Bl[0], 0);
  issueB2(Bl[1], 1);
  asm volatile("s_waitcnt lgkmcnt(0)" ::: "memory");
  asm volatile("s_waitcnt vmcnt(2)" ::: "memory");   // B(0) resident; B(1) in flight
  __builtin_amdgcn_s_barrier();

  int cb = 0;                                    // t % 3
  for (int u = 0; u < 32; ++u) {
    float4 xvn = xv;
    if (u < 31) xvn = *(const float4*)(xrow + (u + 1) * 4);
#pragma unroll
    for (int s = 0; s < 4; ++s) {
      const int t  = u * 4 + s;
      const int tn = t + 1;                         // 1..128
      unsigned short* An = Al[tn & 1];
      unsigned short* Bn = Bl[cb >= 1 ? cb - 1 : 2]; // (t+2) % 3
      if (t < 127) issueB2(Bn, t + 2);
      if (s == 0)      stageA(An, xv.y);
      else if (s == 1) stageA(An, xv.z);
      else if (s == 2) stageA(An, xv.w);
      else if (u < 31) stageA(An, xvn.x);
      else             stageA(An, biasx);           // t=127: bias tile A(128)=er/0
      compute(Al[t & 1], Bl[cb]);
      asm volatile("s_waitcnt lgkmcnt(0)" ::: "memory");  // own A ds_writes drained
      if (t < 127) {
        asm volatile("s_waitcnt vmcnt(2)" ::: "memory");  // B(t+1) done; B(t+2) in flight
      } else {
        asm volatile("s_waitcnt vmcnt(0)" ::: "memory");  // t=127: drain B(128)
      }
      __builtin_amdgcn_s_barrier();
      cb = (cb == 2) ? 0 : cb + 1;
    }
    xv = xvn;
  }
  compute(Al[0], Bl[cb]);   // t=128 (bias tile), cb == 128%3 == 2

  // ---- epilogue: 32x32 C layout col = lane&31, row = (reg&3)+8*(reg>>2)+4*(lane>>5) ----
  const int col = ni * BNB + wc * 32 + l31;
#pragma unroll
  for (int a = 0; a < 2; ++a) {
#pragma unroll
    for (int rg = 0; rg < 16; ++rg) {
      const int rr = m0 + wr * 64 + a * 32 + (rg & 3) + 8 * (rg >> 2) + 4 * (lane >> 5);
      if (rr < Ntot)
        out[(size_t)rr * O_DIM + col] = a ? acc1[rg] : acc0[rg];
    }
  }
}

// ---- fallback (ws too small): simple 2-barrier kernel reading W/b directly ----
__global__ __launch_bounds__(256) void lkg_fb(
    const float* __restrict__ x, const float* __restrict__ e,
    const float* __restrict__ Wf, const float* __restrict__ bf32,
    float* __restrict__ out, int Ntot) {
  const int FBK = 64;
  const int FNT = (KW + 64) / FBK;
  __shared__ unsigned short Alds[128 * 64];
  __shared__ unsigned short Blds[256 * 64];

  const int tid = threadIdx.x, lane = tid & 63, wid = tid >> 6;
  const int wr = wid >> 1, wc = wid & 1, l15 = lane & 15, lk8 = (lane >> 4) * 8;
  const int m0 = (int)blockIdx.x * 128;
  const int srow = tid >> 1, skq = (tid & 1) * 32;
  const int gr = min(m0 + srow, Ntot - 1);

  f32x4 acc[4][8];
#pragma unroll
  for (int a = 0; a < 4; ++a)
#pragma unroll
    for (int c = 0; c < 8; ++c) acc[a][c] = (f32x4){0.f, 0.f, 0.f, 0.f};

  for (int t = 0; t < FNT; ++t) {
    const int k0 = t * FBK;
    float av[32];
    if (k0 < KW) {
      const int r = k0 >> 8, i0 = k0 & 255;
      const float ev = e[(size_t)gr * R_DIM + r];
#pragma unroll
      for (int p = 0; p < 8; ++p) {
        const float4 xvv = *(const float4*)&x[(size_t)gr * I_DIM + i0 + skq + p * 4];
        av[p * 4 + 0] = xvv.x * ev; av[p * 4 + 1] = xvv.y * ev;
        av[p * 4 + 2] = xvv.z * ev; av[p * 4 + 3] = xvv.w * ev;
      }
    } else {
#pragma unroll
      for (int s2 = 0; s2 < 32; ++s2) {
        const int kk = skq + s2;
        av[s2] = (kk < R_DIM) ? e[(size_t)gr * R_DIM + kk] : 0.f;
      }
    }
    const int bo = tid;
    if (k0 < KW) {
      const int r = k0 >> 8, i0 = k0 & 255;
#pragma unroll
      for (int h = 0; h < 4; ++h) {
        float bv[16];
#pragma unroll
        for (int p = 0; p < 4; ++p) {
          const float4 wv =
              *(const float4*)&Wf[((size_t)(r * O_DIM + bo)) * I_DIM + i0 + h * 16 + p * 4];
          bv[p * 4 + 0] = wv.x; bv[p * 4 + 1] = wv.y;
          bv[p * 4 + 2] = wv.z; bv[p * 4 + 3] = wv.w;
        }
#pragma unroll
        for (int g2 = 0; g2 < 2; ++g2) {
          ushort8 pw;
#pragma unroll
          for (int j = 0; j < 8; ++j) pw[j] = f2bf(bv[g2 * 8 + j]);
          *(ushort8*)&Blds[bo * FBK + h * 16 + g2 * 8] = pw;
        }
      }
    } else {
#pragma unroll
      for (int h = 0; h < 8; ++h) {
        ushort8 pw;
#pragma unroll
        for (int j = 0; j < 8; ++j) {
          const int kk = h * 8 + j;
          pw[j] = (kk < R_DIM) ? f2bf(bf32[kk * O_DIM + bo]) : (unsigned short)0;
        }
        *(ushort8*)&Blds[bo * FBK + h * 8] = pw;
      }
    }
#pragma unroll
    for (int h = 0; h < 4; ++h) {
      ushort8 pw;
#pragma unroll
      for (int j = 0; j < 8; ++j) pw[j] = f2bf(av[h * 8 + j]);
      *(ushort8*)&Alds[srow * FBK + skq + h * 8] = pw;
    }
    __syncthreads();
#pragma unroll
    for (int ks = 0; ks < 2; ++ks) {
      short8 af[4]; short8 bfr[8];
#pragma unroll
      for (int fr = 0; fr < 4; ++fr)
        af[fr] = *(const short8*)&Alds[(wr * 64 + fr * 16 + l15) * FBK + ks * 32 + lk8];
#pragma unroll
      for (int fc = 0; fc < 8; ++fc)
        bfr[fc] = *(const short8*)&Blds[(wc * 128 + fc * 16 + l15) * FBK + ks * 32 + lk8];
#pragma unroll
      for (int fr = 0; fr < 4; ++fr)
#pragma unroll
        for (int fc = 0; fc < 8; ++fc)
          acc[fr][fc] =
              __builtin_amdgcn_mfma_f32_16x16x32_bf16(af[fr], bfr[fc], acc[fr][fc], 0, 0, 0);
    }
    __syncthreads();
  }
#pragma unroll
  for (int fr = 0; fr < 4; ++fr) {
    const int r0 = m0 + wr * 64 + fr * 16 + (lane >> 4) * 4;
#pragma unroll
    for (int fc = 0; fc < 8; ++fc) {
      const int col = wc * 128 + fc * 16 + l15;
#pragma unroll
      for (int j = 0; j < 4; ++j) {
        const int rr = r0 + j;
        if (rr < Ntot) out[(size_t)rr * O_DIM + col] = acc[fr][fc][j];
      }
    }
  }
}

extern "C" void kernel_launch(void* const* d_in, const int* in_sizes, int n_in,
                              void* d_out, int out_size, void* d_ws, size_t ws_size,
                              hipStream_t stream) {
  const float* x = (const float*)d_in[0];
  const float* e = (const float*)d_in[1];
  const float* W = (const float*)d_in[2];
  const float* b = (const float*)d_in[3];
  float* out = (float*)d_out;
  const int Ntot = in_sizes[0] / I_DIM;

  const size_t wb_bytes = (size_t)O_DIM * KEXT * sizeof(unsigned short);
  if (ws_size >= wb_bytes) {
    unsigned short* Wb = (unsigned short*)d_ws;
    prep_w<<<(O_DIM * (KEXT / 4)) / 256, 256, 0, stream>>>(W, b, Wb);
    const int nb = ((Ntot + BM - 1) / BM) * 2;
    lkg17<<<nb, NTHR, 0, stream>>>(x, e, Wb, out, Ntot);
  } else {
    lkg_fb<<<(Ntot + 127) / 128, 256, 0, stream>>>(x, e, W, b, out, Ntot);
  }
}